// Round 4
// baseline (13199.225 us; speedup 1.0000x reference)
//
#include <hip/hip_runtime.h>
#include <hip/hip_bf16.h>
#include <math.h>

typedef __attribute__((ext_vector_type(8))) __bf16 bf16x8;
typedef __attribute__((ext_vector_type(8))) short short8;
typedef __attribute__((ext_vector_type(4))) float f32x4;
typedef __attribute__((ext_vector_type(4))) unsigned short ushort4v;

#define AS1 __attribute__((address_space(1)))
#define AS3 __attribute__((address_space(3)))

__device__ __forceinline__ unsigned short f2bf(float f) {
  __hip_bfloat16 h = __float2bfloat16(f);
  return __builtin_bit_cast(unsigned short, h);
}
__device__ __forceinline__ float bf2f(unsigned short s) {
  unsigned int u = ((unsigned int)s) << 16;
  return __builtin_bit_cast(float, u);
}

// ---------- fp32 -> bf16 conversion ----------
__global__ void cvt_f32_bf16(const float4* __restrict__ in,
                             ushort4v* __restrict__ out, size_t n4) {
  size_t i = (size_t)blockIdx.x * blockDim.x + threadIdx.x;
  size_t stride = (size_t)gridDim.x * blockDim.x;
  for (; i < n4; i += stride) {
    float4 v = in[i];
    ushort4v o = { f2bf(v.x), f2bf(v.y), f2bf(v.z), f2bf(v.w) };
    out[i] = o;
  }
}

#define MFMA16(a, b, c) __builtin_amdgcn_mfma_f32_16x16x32_bf16( \
    __builtin_bit_cast(bf16x8, a), __builtin_bit_cast(bf16x8, b), c, 0, 0, 0)

// ---------- 256x256 bf16 GEMM: C = A[M,K] * B[N,K]^T (+bias) ----------
// BK=32, packed LDS ([128 lds-rows][64 elems] per operand: 2 logical rows per
// lds-row), A+B = 32KB/tile, 2 dbuf = 64KB total -> 2 blocks/CU (4 waves/SIMD).
// 8-slot XOR swizzle (slot ^= ldsrow&7): conflict-free ds_read_b128.
// Schedule (T3-minimum, m248/m230): stage(t+1) FIRST, then 12 ds_read + 32
// MFMA (setprio), then one vmcnt(0) + single barrier per tile.
// 8 waves (2M x 4N), per-wave 128x64 out, 16x16x32 MFMA.
// EPI 0: Cb = bf16(gelu(v))          (v = acc + bias[col])
// EPI 1: Cf  = wgt[row*8+eidx] * v
// EPI 2: Cf += wgt[row*8+eidx] * v
// EPI 3: Cf[z*cZ + ...] = wgt[row*8+z] * v   (grouped partials)
template<int EPI>
__global__ __launch_bounds__(512, 4)
void gemm256(const unsigned short* __restrict__ A, size_t aZ,
             const unsigned short* __restrict__ B, size_t bZ,
             const float* __restrict__ bias, size_t biasZ,
             unsigned short* __restrict__ Cb, float* __restrict__ Cf, size_t cZ,
             const float* __restrict__ wgt, int eidx,
             int M, int N, int K) {
  __shared__ alignas(16) unsigned short sm[32768];  // 2 bufs x (A 8192 + B 8192)
  const int tid  = threadIdx.x;
  const int lane = tid & 63;
  const int wid  = tid >> 6;
  const int wr   = wid >> 2;   // 0..1
  const int wc   = wid & 3;    // 0..3
  const int z    = blockIdx.z;

  // XCD-aware swizzle (all grids here have gx*gy % 8 == 0).
  // lin&7 is invariant in blockIdx.y (gx multiple of 8... gx=16 or 4; for gx=4
  // consecutive by share xcd groups too) -> weight-panel sharers colocate.
  const int gx  = gridDim.x;
  const int nwg = gx * gridDim.y;
  const int lin = blockIdx.y * gx + blockIdx.x;
  const int cpx = nwg >> 3;
  const int swb = (lin & 7) * cpx + (lin >> 3);
  const int bm = (swb / gx) * 256;
  const int bn = (swb % gx) * 256;

  const unsigned short* Ab = A + z * aZ + (size_t)bm * K;
  const unsigned short* Bb = B + z * bZ + (size_t)bn * K;

  // staging: phys 16B-unit p = i*512+tid per operand (2 units each).
  // phys p <-> logical: ldsrow=p>>3, sphys=p&7, slog=sphys^(ldsrow&7),
  // row = ldsrow*2 + (slog>>2), chunk c = slog&3  (k = c*8).
  const unsigned short* ga[2];
  const unsigned short* gb[2];
  int ldA[2], ldB[2];
#pragma unroll
  for (int i = 0; i < 2; ++i) {
    const int p    = i * 512 + tid;
    const int lrow = p >> 3;
    const int slog = (p & 7) ^ (lrow & 7);
    const int row  = lrow * 2 + (slog >> 2);
    const int c    = slog & 3;
    ga[i] = Ab + (size_t)row * K + c * 8;
    gb[i] = Bb + (size_t)row * K + c * 8;
    ldA[i] = p * 8;
    ldB[i] = 8192 + p * 8;
  }

  auto stage = [&](int buf) {
    unsigned short* base = &sm[buf * 16384];
#pragma unroll
    for (int i = 0; i < 2; ++i) {
      __builtin_amdgcn_global_load_lds((const AS1 void*)ga[i],
          (AS3 void*)(base + ldA[i]), 16, 0, 0);
      __builtin_amdgcn_global_load_lds((const AS1 void*)gb[i],
          (AS3 void*)(base + ldB[i]), 16, 0, 0);
      ga[i] += 32; gb[i] += 32;
    }
  };

  f32x4 acc[8][4] = {};
  // frag read: row_log = base + (lane&15), k-chunk g = lane>>4.
  // ldsrow = row_log>>1 ; slot = ((lane&1)*4 + g) ^ (ldsrow&7); ldsrow&7 =
  // ((lane&15)>>1) for all frags (bases are multiples of 16 rows).
  const int half  = (lane & 15) >> 1;
  const int sphys = (((lane & 1) << 2) + (lane >> 4)) ^ half;
  const int aoff = wr * 4096 + half * 64 + sphys * 8;          // + mf*512
  const int boff = 8192 + wc * 2048 + half * 64 + sphys * 8;   // + nf*512

  const int NT = K >> 5;   // BK=32
  stage(0);
  asm volatile("s_waitcnt vmcnt(0)" ::: "memory");
  __builtin_amdgcn_s_barrier();
  asm volatile("" ::: "memory");

  int cur = 0;
  for (int t = 0; t < NT; ++t) {
    if (t + 1 < NT) stage(cur ^ 1);          // issue next-tile loads FIRST

    const unsigned short* pa = &sm[cur * 16384 + aoff];
    const unsigned short* pb = &sm[cur * 16384 + boff];
    short8 af[8], bfr[4];
#pragma unroll
    for (int mf = 0; mf < 8; ++mf) af[mf] = *(const short8*)(pa + mf * 512);
#pragma unroll
    for (int nf = 0; nf < 4; ++nf) bfr[nf] = *(const short8*)(pb + nf * 512);
    __builtin_amdgcn_s_setprio(1);
#pragma unroll
    for (int mf = 0; mf < 8; ++mf)
#pragma unroll
      for (int nf = 0; nf < 4; ++nf)
        acc[mf][nf] = MFMA16(af[mf], bfr[nf], acc[mf][nf]);
    __builtin_amdgcn_s_setprio(0);

    if (t + 1 < NT) {
      asm volatile("s_waitcnt vmcnt(0)" ::: "memory");  // next tile landed
      __builtin_amdgcn_s_barrier();                     // single barrier/tile
      asm volatile("" ::: "memory");
    }
    cur ^= 1;
  }

  // epilogue: C/D layout col=lane&15, row=(lane>>4)*4+reg
  const int rbase = bm + wr * 128 + ((lane >> 4) << 2);
  const int cbase = bn + wc * 64 + (lane & 15);
  float wv[8][4];
  if (EPI != 0) {
    const int ei = (EPI == 3) ? z : eidx;
#pragma unroll
    for (int mf = 0; mf < 8; ++mf)
#pragma unroll
      for (int r = 0; r < 4; ++r)
        wv[mf][r] = wgt[(size_t)(rbase + mf * 16 + r) * 8 + ei];
  }
#pragma unroll
  for (int mf = 0; mf < 8; ++mf) {
#pragma unroll
    for (int nf = 0; nf < 4; ++nf) {
      const int col = cbase + nf * 16;
      const float bv = bias[z * biasZ + col];
#pragma unroll
      for (int r = 0; r < 4; ++r) {
        const int row = rbase + mf * 16 + r;
        const float v = acc[mf][nf][r] + bv;
        if (EPI == 0) {
          float g = 0.5f * v * (1.0f + erff(v * 0.70710678118654752f));
          Cb[z * cZ + (size_t)row * N + col] = f2bf(g);
        } else if (EPI == 1) {
          Cf[(size_t)row * N + col] = wv[mf][r] * v;
        } else if (EPI == 2) {
          Cf[(size_t)row * N + col] += wv[mf][r] * v;
        } else {
          Cf[z * cZ + (size_t)row * N + col] = wv[mf][r] * v;
        }
      }
    }
  }
}

// ---------- gate logits (E=8) + softmax, 1 block/token ----------
__global__ void gate_softmax(const unsigned short* __restrict__ g2,
                             const unsigned short* __restrict__ W3,
                             const float* __restrict__ b3,
                             float* __restrict__ wout, int H) {
  const int m = blockIdx.x;
  const int lane = threadIdx.x & 63;
  const int wid  = threadIdx.x >> 6;
  float acc[8] = {0.f, 0.f, 0.f, 0.f, 0.f, 0.f, 0.f, 0.f};
  const unsigned short* grow = g2 + (size_t)m * H;
  for (int k = threadIdx.x * 8; k < H; k += 256 * 8) {
    short8 gv = *(const short8*)(grow + k);
    float gf[8];
#pragma unroll
    for (int j = 0; j < 8; ++j) gf[j] = bf2f((unsigned short)gv[j]);
#pragma unroll
    for (int e = 0; e < 8; ++e) {
      short8 wvv = *(const short8*)(W3 + (size_t)e * H + k);
#pragma unroll
      for (int j = 0; j < 8; ++j) acc[e] += gf[j] * bf2f((unsigned short)wvv[j]);
    }
  }
#pragma unroll
  for (int e = 0; e < 8; ++e)
#pragma unroll
    for (int off = 32; off > 0; off >>= 1) acc[e] += __shfl_down(acc[e], off);
  __shared__ float red[4][8];
  if (lane == 0) {
#pragma unroll
    for (int e = 0; e < 8; ++e) red[wid][e] = acc[e];
  }
  __syncthreads();
  if (threadIdx.x == 0) {
    float l[8], mx = -1e30f, s = 0.f;
#pragma unroll
    for (int e = 0; e < 8; ++e) {
      l[e] = red[0][e] + red[1][e] + red[2][e] + red[3][e] + b3[e];
      mx = fmaxf(mx, l[e]);
    }
#pragma unroll
    for (int e = 0; e < 8; ++e) { l[e] = expf(l[e] - mx); s += l[e]; }
    const float inv = 1.f / s;
#pragma unroll
    for (int e = 0; e < 8; ++e) wout[(size_t)m * 8 + e] = l[e] * inv;
  }
}

// ---------- sum of 8 expert partials ----------
__global__ void reduce8(const float4* __restrict__ in, float4* __restrict__ out,
                        int n4) {
  int i = blockIdx.x * 256 + threadIdx.x;
  const int stride = gridDim.x * 256;
  for (; i < n4; i += stride) {
    float4 s = in[i];
#pragma unroll
    for (int zz = 1; zz < 8; ++zz) {
      float4 v = in[(size_t)zz * n4 + i];
      s.x += v.x; s.y += v.y; s.z += v.z; s.w += v.w;
    }
    out[i] = s;
  }
}

extern "C" void kernel_launch(void* const* d_in, const int* in_sizes, int n_in,
                              void* d_out, int out_size, void* d_ws, size_t ws_size,
                              hipStream_t stream) {
  const float* x   = (const float*)d_in[0];
  const float* gW1 = (const float*)d_in[1];
  const float* gb1 = (const float*)d_in[2];
  const float* gW2 = (const float*)d_in[3];
  const float* gb2 = (const float*)d_in[4];
  const float* gW3 = (const float*)d_in[5];
  const float* gb3 = (const float*)d_in[6];
  const float* eW1 = (const float*)d_in[7];
  const float* eb1 = (const float*)d_in[8];
  const float* eW2 = (const float*)d_in[9];
  const float* eb2 = (const float*)d_in[10];

  const int M = 4096, D = 1024, H = 4096, E = 8;

  float* outP = (float*)d_out;              // [M, D]
  float* wP   = outP + (size_t)M * D;       // [M, E]

  char* ws = (char*)d_ws;
  size_t off = 0;
  auto alloc = [&](size_t bytes) -> void* {
    void* p = ws + off;
    off += (bytes + 255) & ~(size_t)255;
    return p;
  };
  unsigned short* xb   = (unsigned short*)alloc((size_t)M * D * 2);
  unsigned short* gW1b = (unsigned short*)alloc((size_t)H * D * 2);
  unsigned short* gW2b = (unsigned short*)alloc((size_t)H * H * 2);
  unsigned short* gW3b = (unsigned short*)alloc((size_t)E * H * 2);
  unsigned short* eW1b = (unsigned short*)alloc((size_t)E * H * D * 2);
  unsigned short* eW2b = (unsigned short*)alloc((size_t)E * D * H * 2);
  unsigned short* g1b  = (unsigned short*)alloc((size_t)M * H * 2);
  unsigned short* g2b  = (unsigned short*)alloc((size_t)M * H * 2);
  const size_t base_off = off;

  // tier sizing
  const size_t hall_b = (size_t)E * M * H * 2;   // 256 MB
  const size_t eo_b   = (size_t)E * M * D * 4;   // 128 MB
  const int tier = (ws_size >= base_off + hall_b + eo_b) ? 1
                 : (ws_size >= base_off + hall_b)        ? 2
                                                         : 3;

  auto cvt = [&](const float* src, unsigned short* dst, size_t n) {
    size_t n4 = n >> 2;
    size_t b = (n4 + 255) >> 8;
    if (b > 2048) b = 2048;
    cvt_f32_bf16<<<dim3((unsigned)b), dim3(256), 0, stream>>>(
        (const float4*)src, (ushort4v*)dst, n4);
  };
  cvt(x,   xb,   (size_t)M * D);
  cvt(gW1, gW1b, (size_t)H * D);
  cvt(gW2, gW2b, (size_t)H * H);
  cvt(gW3, gW3b, (size_t)E * H);
  cvt(eW1, eW1b, (size_t)E * H * D);
  cvt(eW2, eW2b, (size_t)E * D * H);

  // gate1: g1 = gelu(x @ gW1^T + gb1)   [M,H], K=D
  gemm256<0><<<dim3(H / 256, M / 256, 1), dim3(512), 0, stream>>>(
      xb, 0, gW1b, 0, gb1, 0, g1b, nullptr, 0, nullptr, 0, M, H, D);
  // gate2: g2 = gelu(g1 @ gW2^T + gb2)  [M,H], K=H
  gemm256<0><<<dim3(H / 256, M / 256, 1), dim3(512), 0, stream>>>(
      g1b, 0, gW2b, 0, gb2, 0, g2b, nullptr, 0, nullptr, 0, M, H, H);
  // softmax weights
  gate_softmax<<<dim3(M), dim3(256), 0, stream>>>(g2b, gW3b, gb3, wP, H);

  if (tier <= 2) {
    unsigned short* h_all = (unsigned short*)alloc(hall_b);
    // expert layer 1, all experts grouped: h_all[e] = gelu(x @ eW1[e]^T + eb1[e])
    gemm256<0><<<dim3(H / 256, M / 256, E), dim3(512), 0, stream>>>(
        xb, 0, eW1b, (size_t)H * D, eb1, H, h_all, nullptr, (size_t)M * H,
        nullptr, 0, M, H, D);
    if (tier == 1) {
      float* eo_all = (float*)alloc(eo_b);
      // expert layer 2 grouped -> weighted partials
      gemm256<3><<<dim3(D / 256, M / 256, E), dim3(512), 0, stream>>>(
          h_all, (size_t)M * H, eW2b, (size_t)D * H, eb2, D,
          nullptr, eo_all, (size_t)M * D, wP, 0, M, D, H);
      reduce8<<<dim3(2048), dim3(256), 0, stream>>>(
          (const float4*)eo_all, (float4*)outP, (int)((size_t)M * D / 4));
    } else {
      for (int e = 0; e < E; ++e) {
        if (e == 0)
          gemm256<1><<<dim3(D / 256, M / 256, 1), dim3(512), 0, stream>>>(
              h_all + (size_t)e * M * H, 0, eW2b + (size_t)e * D * H, 0,
              eb2 + (size_t)e * D, 0, nullptr, outP, 0, wP, e, M, D, H);
        else
          gemm256<2><<<dim3(D / 256, M / 256, 1), dim3(512), 0, stream>>>(
              h_all + (size_t)e * M * H, 0, eW2b + (size_t)e * D * H, 0,
              eb2 + (size_t)e * D, 0, nullptr, outP, 0, wP, e, M, D, H);
      }
    }
  } else {
    // tier 3: sequential, h aliases g1b (free after softmax)
    unsigned short* hb = g1b;
    for (int e = 0; e < E; ++e) {
      gemm256<0><<<dim3(H / 256, M / 256, 1), dim3(512), 0, stream>>>(
          xb, 0, eW1b + (size_t)e * H * D, 0, eb1 + (size_t)e * H, 0,
          hb, nullptr, 0, nullptr, 0, M, H, D);
      if (e == 0)
        gemm256<1><<<dim3(D / 256, M / 256, 1), dim3(512), 0, stream>>>(
            hb, 0, eW2b + (size_t)e * D * H, 0, eb2 + (size_t)e * D, 0,
            nullptr, outP, 0, wP, e, M, D, H);
      else
        gemm256<2><<<dim3(D / 256, M / 256, 1), dim3(512), 0, stream>>>(
            hb, 0, eW2b + (size_t)e * D * H, 0, eb2 + (size_t)e * D, 0,
            nullptr, outP, 0, wP, e, M, D, H);
    }
  }
}

// Round 5
// 1719.327 us; speedup vs baseline: 7.6770x; 7.6770x over previous
//
#include <hip/hip_runtime.h>
#include <hip/hip_bf16.h>
#include <math.h>

typedef __attribute__((ext_vector_type(8))) __bf16 bf16x8;
typedef __attribute__((ext_vector_type(8))) short short8;
typedef __attribute__((ext_vector_type(4))) float f32x4;
typedef __attribute__((ext_vector_type(4))) unsigned short ushort4v;

#define AS1 __attribute__((address_space(1)))
#define AS3 __attribute__((address_space(3)))

__device__ __forceinline__ unsigned short f2bf(float f) {
  __hip_bfloat16 h = __float2bfloat16(f);
  return __builtin_bit_cast(unsigned short, h);
}
__device__ __forceinline__ float bf2f(unsigned short s) {
  unsigned int u = ((unsigned int)s) << 16;
  return __builtin_bit_cast(float, u);
}

// ---------- fp32 -> bf16 conversion ----------
__global__ void cvt_f32_bf16(const float4* __restrict__ in,
                             ushort4v* __restrict__ out, size_t n4) {
  size_t i = (size_t)blockIdx.x * blockDim.x + threadIdx.x;
  size_t stride = (size_t)gridDim.x * blockDim.x;
  for (; i < n4; i += stride) {
    float4 v = in[i];
    ushort4v o = { f2bf(v.x), f2bf(v.y), f2bf(v.z), f2bf(v.w) };
    out[i] = o;
  }
}

#define MFMA16(a, b, c) __builtin_amdgcn_mfma_f32_16x16x32_bf16( \
    __builtin_bit_cast(bf16x8, a), __builtin_bit_cast(bf16x8, b), c, 0, 0, 0)

// ---------- 256x256 bf16 GEMM: C = A[M,K] * B[N,K]^T (+bias) ----------
// T3+T4 fine-phase schedule with a 10-slot half-tile LDS ring (160 KB):
//   staging unit = half-tile (128 rows x 64 k = 16 KB), stream order per
//   K-tile t: A0,A1,B0,B1 (half index H = 4t+kind), slot = H mod 10.
//   Phase p of tile t stages half 4t+6+p (lead 6); K-tile boundary waits
//   vmcnt(4) (2 half-tiles remain in flight) -- never drains in steady state.
//   Safety: slot written by half H was last read as half H-10 (tile t-1),
//   whose reads completed before this tile's boundary barrier; in-flight
//   halves 4t+4..4t+9 are disjoint (mod 10) from read slots 4t..4t+3.
// Per K-tile: 4 quadrant phases (m-half x n-pair), each:
//   {ds_read (12/4/8/0 x b128); stage 1 half; barrier; setprio(1);
//    16 x MFMA; setprio(0); barrier}.
// 8 waves (2M x 4N), per-wave 128x64 out, 16x16x32 MFMA.
// LDS half-slot layout: [128 rows][8 slots of 8 elems], slot = chunk^(row&7)
// (round-2-verified zero bank conflicts).
// EPI 0: Cb = bf16(gelu(v))          (v = acc + bias[col])
// EPI 1: Cf  = wgt[row*8+eidx] * v
// EPI 2: Cf += wgt[row*8+eidx] * v
// EPI 3: Cf[z*cZ + ...] = wgt[row*8+z] * v   (grouped partials)
template<int EPI>
__global__ __launch_bounds__(512, 2)
void gemm256(const unsigned short* __restrict__ A, size_t aZ,
             const unsigned short* __restrict__ B, size_t bZ,
             const float* __restrict__ bias, size_t biasZ,
             unsigned short* __restrict__ Cb, float* __restrict__ Cf, size_t cZ,
             const float* __restrict__ wgt, int eidx,
             int M, int N, int K) {
  __shared__ alignas(16) unsigned short sm[81920];  // 10 slots x 8192 = 160 KB
  const int tid  = threadIdx.x;
  const int lane = tid & 63;
  const int wid  = tid >> 6;
  const int wr   = wid >> 2;   // 0..1  -> A-half
  const int wc   = wid & 3;    // 0..3  -> B-half = wc>>1
  const int z    = blockIdx.z;

  // XCD-aware swizzle (all grids here have gx*gy % 8 == 0)
  const int gx  = gridDim.x;
  const int nwg = gx * gridDim.y;
  const int lin = blockIdx.y * gx + blockIdx.x;
  const int cpx = nwg >> 3;
  const int swb = (lin & 7) * cpx + (lin >> 3);
  const int bm = (swb / gx) * 256;
  const int bn = (swb % gx) * 256;

  const unsigned short* Ab = A + z * aZ + (size_t)bm * K;
  const unsigned short* Bb = B + z * bZ + (size_t)bn * K;

  // staging: 2 x 16B units per thread per half-tile.
  // unit p = i*512+tid: row = p>>3 (0..127 within half), phys slot p&7 holds
  // logical chunk q = (p&7)^(row&7)  -> source k-offset q*8.
  const unsigned short* gA[2];
  const unsigned short* gB[2];
  int ldo[2];
#pragma unroll
  for (int i = 0; i < 2; ++i) {
    const int p   = i * 512 + tid;
    const int row = p >> 3;
    const int q   = (p & 7) ^ (row & 7);
    gA[i] = Ab + (size_t)row * K + q * 8;
    gB[i] = Bb + (size_t)row * K + q * 8;
    ldo[i] = p * 8;
  }

  const int NT   = K >> 6;      // BK = 64
  const int maxH = NT * 4;

  auto stage = [&](int slot, int H) {
    const int T = H >> 2, kind = H & 3;
    const size_t add = (size_t)(kind & 1) * ((size_t)128 * K) + (size_t)T * 64;
    const unsigned short* s0 = (kind & 2) ? gB[0] : gA[0];
    const unsigned short* s1 = (kind & 2) ? gB[1] : gA[1];
    unsigned short* base = &sm[slot * 8192];
    __builtin_amdgcn_global_load_lds((const AS1 void*)(s0 + add),
        (AS3 void*)(base + ldo[0]), 16, 0, 0);
    __builtin_amdgcn_global_load_lds((const AS1 void*)(s1 + add),
        (AS3 void*)(base + ldo[1]), 16, 0, 0);
  };

  f32x4 acc[8][4] = {};
  const int laneq = lane & 15;
  const int rowe  = laneq * 64;                         // row offset (elems)
  const int sw0   = (((lane >> 4)    ) ^ (laneq & 7)) * 8;  // kk=0 chunk slot
  const int sw1   = (((lane >> 4) + 4) ^ (laneq & 7)) * 8;  // kk=1 chunk slot
  const int bhalf = (wc & 1) * 4096;                    // 64 rows into B-half

  // prologue: stage halves 0..5 (tile 0 + A-halves of tile 1)
#pragma unroll
  for (int H = 0; H < 6; ++H)
    if (H < maxH) stage(H, H);

  int sA = wr;              // slot of my A-half for tile t
  int sB = 2 + (wc >> 1);   // slot of my B-half for tile t
  int stH = 6, stS = 6;     // staging stream position

  for (int t = 0; t < NT; ++t) {
    if (t + 1 < NT) asm volatile("s_waitcnt vmcnt(4)" ::: "memory");
    else            asm volatile("s_waitcnt vmcnt(0)" ::: "memory");
    __builtin_amdgcn_s_barrier();     // tile t resident for all waves
    asm volatile("" ::: "memory");

    const unsigned short* pa = &sm[sA * 8192 + rowe];
    const unsigned short* pb = &sm[sB * 8192 + bhalf + rowe];
    short8 af[4][2], bf[4][2];
#pragma unroll
    for (int q = 0; q < 4; ++q) {
      if (q == 0) {
#pragma unroll
        for (int j = 0; j < 4; ++j) {
          af[j][0] = *(const short8*)(pa + j * 1024 + sw0);
          af[j][1] = *(const short8*)(pa + j * 1024 + sw1);
        }
#pragma unroll
        for (int n = 0; n < 2; ++n) {
          bf[n][0] = *(const short8*)(pb + n * 1024 + sw0);
          bf[n][1] = *(const short8*)(pb + n * 1024 + sw1);
        }
      } else if (q == 1) {
#pragma unroll
        for (int n = 2; n < 4; ++n) {
          bf[n][0] = *(const short8*)(pb + n * 1024 + sw0);
          bf[n][1] = *(const short8*)(pb + n * 1024 + sw1);
        }
      } else if (q == 2) {
#pragma unroll
        for (int j = 0; j < 4; ++j) {
          af[j][0] = *(const short8*)(pa + (4 + j) * 1024 + sw0);
          af[j][1] = *(const short8*)(pa + (4 + j) * 1024 + sw1);
        }
      }
      if (stH < maxH) stage(stS, stH);
      ++stH; stS = (stS == 9) ? 0 : stS + 1;

      __builtin_amdgcn_s_barrier();
      asm volatile("" ::: "memory");
      __builtin_amdgcn_s_setprio(1);
      const int mb = (q >> 1) << 2;
      const int nb = (q & 1) << 1;
#pragma unroll
      for (int j = 0; j < 4; ++j)
#pragma unroll
        for (int n = 0; n < 2; ++n)
#pragma unroll
          for (int k = 0; k < 2; ++k)
            acc[mb + j][nb + n] =
                MFMA16(af[j][k], bf[nb + n][k], acc[mb + j][nb + n]);
      __builtin_amdgcn_s_setprio(0);
      asm volatile("" ::: "memory");
      __builtin_amdgcn_s_barrier();
      asm volatile("" ::: "memory");
    }
    sA += 4; if (sA >= 10) sA -= 10;
    sB += 4; if (sB >= 10) sB -= 10;
  }

  // epilogue: C/D layout col=lane&15, row=(lane>>4)*4+reg
  const int rbase = bm + wr * 128 + ((lane >> 4) << 2);
  const int cbase = bn + wc * 64 + (lane & 15);
  float wv[8][4];
  if (EPI != 0) {
    const int ei = (EPI == 3) ? z : eidx;
#pragma unroll
    for (int mf = 0; mf < 8; ++mf)
#pragma unroll
      for (int r = 0; r < 4; ++r)
        wv[mf][r] = wgt[(size_t)(rbase + mf * 16 + r) * 8 + ei];
  }
#pragma unroll
  for (int mf = 0; mf < 8; ++mf) {
#pragma unroll
    for (int nf = 0; nf < 4; ++nf) {
      const int col = cbase + nf * 16;
      const float bv = bias[z * biasZ + col];
#pragma unroll
      for (int r = 0; r < 4; ++r) {
        const int row = rbase + mf * 16 + r;
        const float v = acc[mf][nf][r] + bv;
        if (EPI == 0) {
          float g = 0.5f * v * (1.0f + erff(v * 0.70710678118654752f));
          Cb[z * cZ + (size_t)row * N + col] = f2bf(g);
        } else if (EPI == 1) {
          Cf[(size_t)row * N + col] = wv[mf][r] * v;
        } else if (EPI == 2) {
          Cf[(size_t)row * N + col] += wv[mf][r] * v;
        } else {
          Cf[z * cZ + (size_t)row * N + col] = wv[mf][r] * v;
        }
      }
    }
  }
}

// ---------- gate logits (E=8) + softmax, 1 block/token ----------
__global__ void gate_softmax(const unsigned short* __restrict__ g2,
                             const unsigned short* __restrict__ W3,
                             const float* __restrict__ b3,
                             float* __restrict__ wout, int H) {
  const int m = blockIdx.x;
  const int lane = threadIdx.x & 63;
  const int wid  = threadIdx.x >> 6;
  float acc[8] = {0.f, 0.f, 0.f, 0.f, 0.f, 0.f, 0.f, 0.f};
  const unsigned short* grow = g2 + (size_t)m * H;
  for (int k = threadIdx.x * 8; k < H; k += 256 * 8) {
    short8 gv = *(const short8*)(grow + k);
    float gf[8];
#pragma unroll
    for (int j = 0; j < 8; ++j) gf[j] = bf2f((unsigned short)gv[j]);
#pragma unroll
    for (int e = 0; e < 8; ++e) {
      short8 wvv = *(const short8*)(W3 + (size_t)e * H + k);
#pragma unroll
      for (int j = 0; j < 8; ++j) acc[e] += gf[j] * bf2f((unsigned short)wvv[j]);
    }
  }
#pragma unroll
  for (int e = 0; e < 8; ++e)
#pragma unroll
    for (int off = 32; off > 0; off >>= 1) acc[e] += __shfl_down(acc[e], off);
  __shared__ float red[4][8];
  if (lane == 0) {
#pragma unroll
    for (int e = 0; e < 8; ++e) red[wid][e] = acc[e];
  }
  __syncthreads();
  if (threadIdx.x == 0) {
    float l[8], mx = -1e30f, s = 0.f;
#pragma unroll
    for (int e = 0; e < 8; ++e) {
      l[e] = red[0][e] + red[1][e] + red[2][e] + red[3][e] + b3[e];
      mx = fmaxf(mx, l[e]);
    }
#pragma unroll
    for (int e = 0; e < 8; ++e) { l[e] = expf(l[e] - mx); s += l[e]; }
    const float inv = 1.f / s;
#pragma unroll
    for (int e = 0; e < 8; ++e) wout[(size_t)m * 8 + e] = l[e] * inv;
  }
}

// ---------- sum of 8 expert partials ----------
__global__ void reduce8(const float4* __restrict__ in, float4* __restrict__ out,
                        int n4) {
  int i = blockIdx.x * 256 + threadIdx.x;
  const int stride = gridDim.x * 256;
  for (; i < n4; i += stride) {
    float4 s = in[i];
#pragma unroll
    for (int zz = 1; zz < 8; ++zz) {
      float4 v = in[(size_t)zz * n4 + i];
      s.x += v.x; s.y += v.y; s.z += v.z; s.w += v.w;
    }
    out[i] = s;
  }
}

extern "C" void kernel_launch(void* const* d_in, const int* in_sizes, int n_in,
                              void* d_out, int out_size, void* d_ws, size_t ws_size,
                              hipStream_t stream) {
  const float* x   = (const float*)d_in[0];
  const float* gW1 = (const float*)d_in[1];
  const float* gb1 = (const float*)d_in[2];
  const float* gW2 = (const float*)d_in[3];
  const float* gb2 = (const float*)d_in[4];
  const float* gW3 = (const float*)d_in[5];
  const float* gb3 = (const float*)d_in[6];
  const float* eW1 = (const float*)d_in[7];
  const float* eb1 = (const float*)d_in[8];
  const float* eW2 = (const float*)d_in[9];
  const float* eb2 = (const float*)d_in[10];

  const int M = 4096, D = 1024, H = 4096, E = 8;

  float* outP = (float*)d_out;              // [M, D]
  float* wP   = outP + (size_t)M * D;       // [M, E]

  char* ws = (char*)d_ws;
  size_t off = 0;
  auto alloc = [&](size_t bytes) -> void* {
    void* p = ws + off;
    off += (bytes + 255) & ~(size_t)255;
    return p;
  };
  unsigned short* xb   = (unsigned short*)alloc((size_t)M * D * 2);
  unsigned short* gW1b = (unsigned short*)alloc((size_t)H * D * 2);
  unsigned short* gW2b = (unsigned short*)alloc((size_t)H * H * 2);
  unsigned short* gW3b = (unsigned short*)alloc((size_t)E * H * 2);
  unsigned short* eW1b = (unsigned short*)alloc((size_t)E * H * D * 2);
  unsigned short* eW2b = (unsigned short*)alloc((size_t)E * D * H * 2);
  unsigned short* g1b  = (unsigned short*)alloc((size_t)M * H * 2);
  unsigned short* g2b  = (unsigned short*)alloc((size_t)M * H * 2);
  const size_t base_off = off;

  // tier sizing
  const size_t hall_b = (size_t)E * M * H * 2;   // 256 MB
  const size_t eo_b   = (size_t)E * M * D * 4;   // 128 MB
  const int tier = (ws_size >= base_off + hall_b + eo_b) ? 1
                 : (ws_size >= base_off + hall_b)        ? 2
                                                         : 3;

  auto cvt = [&](const float* src, unsigned short* dst, size_t n) {
    size_t n4 = n >> 2;
    size_t b = (n4 + 255) >> 8;
    if (b > 2048) b = 2048;
    cvt_f32_bf16<<<dim3((unsigned)b), dim3(256), 0, stream>>>(
        (const float4*)src, (ushort4v*)dst, n4);
  };
  cvt(x,   xb,   (size_t)M * D);
  cvt(gW1, gW1b, (size_t)H * D);
  cvt(gW2, gW2b, (size_t)H * H);
  cvt(gW3, gW3b, (size_t)E * H);
  cvt(eW1, eW1b, (size_t)E * H * D);
  cvt(eW2, eW2b, (size_t)E * D * H);

  // gate1: g1 = gelu(x @ gW1^T + gb1)   [M,H], K=D
  gemm256<0><<<dim3(H / 256, M / 256, 1), dim3(512), 0, stream>>>(
      xb, 0, gW1b, 0, gb1, 0, g1b, nullptr, 0, nullptr, 0, M, H, D);
  // gate2: g2 = gelu(g1 @ gW2^T + gb2)  [M,H], K=H
  gemm256<0><<<dim3(H / 256, M / 256, 1), dim3(512), 0, stream>>>(
      g1b, 0, gW2b, 0, gb2, 0, g2b, nullptr, 0, nullptr, 0, M, H, H);
  // softmax weights
  gate_softmax<<<dim3(M), dim3(256), 0, stream>>>(g2b, gW3b, gb3, wP, H);

  if (tier <= 2) {
    unsigned short* h_all = (unsigned short*)alloc(hall_b);
    // expert layer 1, all experts grouped: h_all[e] = gelu(x @ eW1[e]^T + eb1[e])
    gemm256<0><<<dim3(H / 256, M / 256, E), dim3(512), 0, stream>>>(
        xb, 0, eW1b, (size_t)H * D, eb1, H, h_all, nullptr, (size_t)M * H,
        nullptr, 0, M, H, D);
    if (tier == 1) {
      float* eo_all = (float*)alloc(eo_b);
      // expert layer 2 grouped -> weighted partials
      gemm256<3><<<dim3(D / 256, M / 256, E), dim3(512), 0, stream>>>(
          h_all, (size_t)M * H, eW2b, (size_t)D * H, eb2, D,
          nullptr, eo_all, (size_t)M * D, wP, 0, M, D, H);
      reduce8<<<dim3(2048), dim3(256), 0, stream>>>(
          (const float4*)eo_all, (float4*)outP, (int)((size_t)M * D / 4));
    } else {
      for (int e = 0; e < E; ++e) {
        if (e == 0)
          gemm256<1><<<dim3(D / 256, M / 256, 1), dim3(512), 0, stream>>>(
              h_all + (size_t)e * M * H, 0, eW2b + (size_t)e * D * H, 0,
              eb2 + (size_t)e * D, 0, nullptr, outP, 0, wP, e, M, D, H);
        else
          gemm256<2><<<dim3(D / 256, M / 256, 1), dim3(512), 0, stream>>>(
              h_all + (size_t)e * M * H, 0, eW2b + (size_t)e * D * H, 0,
              eb2 + (size_t)e * D, 0, nullptr, outP, 0, wP, e, M, D, H);
      }
    }
  } else {
    // tier 3: sequential, h aliases g1b (free after softmax)
    unsigned short* hb = g1b;
    for (int e = 0; e < E; ++e) {
      gemm256<0><<<dim3(H / 256, M / 256, 1), dim3(512), 0, stream>>>(
          xb, 0, eW1b + (size_t)e * H * D, 0, eb1 + (size_t)e * H, 0,
          hb, nullptr, 0, nullptr, 0, M, H, D);
      if (e == 0)
        gemm256<1><<<dim3(D / 256, M / 256, 1), dim3(512), 0, stream>>>(
            hb, 0, eW2b + (size_t)e * D * H, 0, eb2 + (size_t)e * D, 0,
            nullptr, outP, 0, wP, e, M, D, H);
      else
        gemm256<2><<<dim3(D / 256, M / 256, 1), dim3(512), 0, stream>>>(
            hb, 0, eW2b + (size_t)e * D * H, 0, eb2 + (size_t)e * D, 0,
            nullptr, outP, 0, wP, e, M, D, H);
    }
  }
}

// Round 6
// 1507.626 us; speedup vs baseline: 8.7550x; 1.1404x over previous
//
#include <hip/hip_runtime.h>
#include <hip/hip_bf16.h>
#include <math.h>

typedef __attribute__((ext_vector_type(8))) __bf16 bf16x8;
typedef __attribute__((ext_vector_type(8))) short short8;
typedef __attribute__((ext_vector_type(4))) float f32x4;
typedef __attribute__((ext_vector_type(4))) unsigned short ushort4v;

#define AS1 __attribute__((address_space(1)))
#define AS3 __attribute__((address_space(3)))

__device__ __forceinline__ unsigned short f2bf(float f) {
  __hip_bfloat16 h = __float2bfloat16(f);
  return __builtin_bit_cast(unsigned short, h);
}
__device__ __forceinline__ float bf2f(unsigned short s) {
  unsigned int u = ((unsigned int)s) << 16;
  return __builtin_bit_cast(float, u);
}

// fast exact-shape gelu: 0.5*v*(1+erf(v/sqrt2)), erf via A&S 7.1.26 (|err|<1.5e-7)
__device__ __forceinline__ float fast_gelu(float v) {
  const float x = v * 0.70710678118654752f;
  const float a = __builtin_fabsf(x);
  const float t = __builtin_amdgcn_rcpf(__builtin_fmaf(0.3275911f, a, 1.0f));
  float p = __builtin_fmaf(t, 1.061405429f, -1.453152027f);
  p = __builtin_fmaf(t, p, 1.421413741f);
  p = __builtin_fmaf(t, p, -0.284496736f);
  p = __builtin_fmaf(t, p, 0.254829592f);
  p = p * t;
  const float e = __builtin_amdgcn_exp2f(-a * a * 1.4426950408889634f);
  const float erfa = __builtin_fmaf(-p, e, 1.0f);
  const float erfx = __builtin_copysignf(erfa, x);
  return 0.5f * v * (1.0f + erfx);
}

// ---------- fp32 -> bf16 conversion ----------
__global__ void cvt_f32_bf16(const float4* __restrict__ in,
                             ushort4v* __restrict__ out, size_t n4) {
  size_t i = (size_t)blockIdx.x * blockDim.x + threadIdx.x;
  size_t stride = (size_t)gridDim.x * blockDim.x;
  for (; i < n4; i += stride) {
    float4 v = in[i];
    ushort4v o = { f2bf(v.x), f2bf(v.y), f2bf(v.z), f2bf(v.w) };
    out[i] = o;
  }
}

#define MFMA16(a, b, c) __builtin_amdgcn_mfma_f32_16x16x32_bf16( \
    __builtin_bit_cast(bf16x8, a), __builtin_bit_cast(bf16x8, b), c, 0, 0, 0)

// ---------- 256x256 bf16 GEMM: C = A[M,K](lda) * B[N,K]^T (+bias) ----------
// De-lockstepped pipeline: 10-slot half-tile LDS ring (160 KB), lead 6 halves,
// ONE barrier per K-tile (boundary vmcnt(4)+s_barrier only; slot-safety proof:
// staged slots (4t+6..9)%10 disjoint from read slots (4t..4t+3)%10, cross-tile
// overwrite fenced by the boundary barrier). Within a tile, 4 phases with
// one-phase READ-AHEAD: phase p ds_reads quadrant p's frags and MFMAs quadrant
// p-1 (operand sets disjoint -> no WAR, lgkm slack >= 1 phase). Waves drift
// freely so LDS bursts of one wave overlap MFMA of others.
// Quadrants of the wave's 128x64: q00(A0,B0) q01(A0,B1) q10(A1,B0) q11(A1,B1).
// EPI 0: Cb = bf16(gelu(v))          (v = acc + bias[col])
// EPI 1: Cf  = wgt[row*8+eidx] * v
// EPI 2: Cf += wgt[row*8+eidx] * v
// EPI 3: Cf[z*cZ + ...] = wgt[row*8+z] * v   (grouped partials)
template<int EPI>
__global__ __launch_bounds__(512, 2)
void gemm256(const unsigned short* __restrict__ A, size_t aZ, int lda,
             const unsigned short* __restrict__ B, size_t bZ,
             const float* __restrict__ bias, size_t biasZ,
             unsigned short* __restrict__ Cb, float* __restrict__ Cf, size_t cZ,
             const float* __restrict__ wgt, int eidx,
             int M, int N, int K) {
  __shared__ alignas(16) unsigned short sm[81920];  // 10 slots x 8192 = 160 KB
  const int tid  = threadIdx.x;
  const int lane = tid & 63;
  const int wid  = tid >> 6;
  const int wr   = wid >> 2;   // 0..1  -> A-half
  const int wc   = wid & 3;    // 0..3  -> B-half = wc>>1
  const int z    = blockIdx.z;

  // XCD-aware swizzle (all grids here have gx*gy % 8 == 0)
  const int gx  = gridDim.x;
  const int nwg = gx * gridDim.y;
  const int lin = blockIdx.y * gx + blockIdx.x;
  const int cpx = nwg >> 3;
  const int swb = (lin & 7) * cpx + (lin >> 3);
  const int bm = (swb / gx) * 256;
  const int bn = (swb % gx) * 256;

  const unsigned short* Ab = A + z * aZ + (size_t)bm * lda;  // uniform (SGPR)
  const unsigned short* Bb = B + z * bZ + (size_t)bn * K;

  // staging: 2 x 16B units per thread per half-tile; u32 per-lane offsets.
  // unit p = i*512+tid: row = p>>3 (0..127 in half), phys slot p&7 holds
  // logical chunk q = (p&7)^(row&7).
  unsigned aoffu[2], boffu[2];
  int ldo[2];
#pragma unroll
  for (int i = 0; i < 2; ++i) {
    const int p   = i * 512 + tid;
    const int row = p >> 3;
    const int q   = (p & 7) ^ (row & 7);
    aoffu[i] = (unsigned)(row * lda + q * 8);
    boffu[i] = (unsigned)(row * K + q * 8);
    ldo[i] = p * 8;
  }

  const int NT   = K >> 6;      // BK = 64
  const int maxH = NT * 4;

  auto stage = [&](int slot, int H) {
    const unsigned T64 = (unsigned)(H >> 2) * 64u;
    const int kind = H & 3;
    unsigned short* base = &sm[slot * 8192];
    if (kind & 2) {
      const unsigned add = (kind & 1) ? (unsigned)(128 * K) + T64 : T64;
      __builtin_amdgcn_global_load_lds((const AS1 void*)(Bb + boffu[0] + add),
          (AS3 void*)(base + ldo[0]), 16, 0, 0);
      __builtin_amdgcn_global_load_lds((const AS1 void*)(Bb + boffu[1] + add),
          (AS3 void*)(base + ldo[1]), 16, 0, 0);
    } else {
      const unsigned add = (kind & 1) ? (unsigned)(128 * lda) + T64 : T64;
      __builtin_amdgcn_global_load_lds((const AS1 void*)(Ab + aoffu[0] + add),
          (AS3 void*)(base + ldo[0]), 16, 0, 0);
      __builtin_amdgcn_global_load_lds((const AS1 void*)(Ab + aoffu[1] + add),
          (AS3 void*)(base + ldo[1]), 16, 0, 0);
    }
  };

  f32x4 acc[8][4] = {};
  const int laneq = lane & 15;
  const int rowe  = laneq * 64;                             // row offset (elems)
  const int sw0   = (((lane >> 4)    ) ^ (laneq & 7)) * 8;  // kk=0 chunk slot
  const int sw1   = (((lane >> 4) + 4) ^ (laneq & 7)) * 8;  // kk=1 chunk slot
  const int bhalf = (wc & 1) * 4096;                        // 64 rows into B-half

  // prologue: stage halves 0..5 (lead 6)
#pragma unroll
  for (int H = 0; H < 6; ++H)
    if (H < maxH) stage(H, H);

  int sA = wr;              // slot of my A-half for tile t
  int sB = 2 + (wc >> 1);   // slot of my B-half for tile t
  int stH = 6, stS = 6;     // staging stream position

  short8 afA[4][2], afB[4][2], bfA[2][2], bfB[2][2];

  auto stage_step = [&]() {
    if (stH < maxH) stage(stS, stH);
    ++stH; stS = (stS == 9) ? 0 : stS + 1;
  };

  for (int t = 0; t < NT; ++t) {
    // ---- K-tile boundary (the ONLY barrier) ----
    if (t + 1 < NT) asm volatile("s_waitcnt vmcnt(4)" ::: "memory");
    else            asm volatile("s_waitcnt vmcnt(0)" ::: "memory");
    __builtin_amdgcn_s_barrier();
    asm volatile("" ::: "memory");   // no LDS read hoists above the barrier

    const unsigned short* pa = &sm[sA * 8192 + rowe];
    const unsigned short* pb = &sm[sB * 8192 + bhalf + rowe];

    // ---- phase 0: read A0,B0(t); MFMA q11(t-1) ----
#pragma unroll
    for (int j = 0; j < 4; ++j) {
      afA[j][0] = *(const short8*)(pa + j * 1024 + sw0);
      afA[j][1] = *(const short8*)(pa + j * 1024 + sw1);
    }
#pragma unroll
    for (int n = 0; n < 2; ++n) {
      bfA[n][0] = *(const short8*)(pb + n * 1024 + sw0);
      bfA[n][1] = *(const short8*)(pb + n * 1024 + sw1);
    }
    stage_step();
    if (t) {
      __builtin_amdgcn_s_setprio(1);
#pragma unroll
      for (int j = 0; j < 4; ++j)
#pragma unroll
        for (int n = 0; n < 2; ++n)
#pragma unroll
          for (int k = 0; k < 2; ++k)
            acc[4 + j][2 + n] = MFMA16(afB[j][k], bfB[n][k], acc[4 + j][2 + n]);
      __builtin_amdgcn_s_setprio(0);
    }

    // ---- phase 1: read B1(t); MFMA q00 ----
#pragma unroll
    for (int n = 0; n < 2; ++n) {
      bfB[n][0] = *(const short8*)(pb + (2 + n) * 1024 + sw0);
      bfB[n][1] = *(const short8*)(pb + (2 + n) * 1024 + sw1);
    }
    stage_step();
    __builtin_amdgcn_s_setprio(1);
#pragma unroll
    for (int j = 0; j < 4; ++j)
#pragma unroll
      for (int n = 0; n < 2; ++n)
#pragma unroll
        for (int k = 0; k < 2; ++k)
          acc[j][n] = MFMA16(afA[j][k], bfA[n][k], acc[j][n]);
    __builtin_amdgcn_s_setprio(0);

    // ---- phase 2: read A1(t); MFMA q01 ----
#pragma unroll
    for (int j = 0; j < 4; ++j) {
      afB[j][0] = *(const short8*)(pa + (4 + j) * 1024 + sw0);
      afB[j][1] = *(const short8*)(pa + (4 + j) * 1024 + sw1);
    }
    stage_step();
    __builtin_amdgcn_s_setprio(1);
#pragma unroll
    for (int j = 0; j < 4; ++j)
#pragma unroll
      for (int n = 0; n < 2; ++n)
#pragma unroll
        for (int k = 0; k < 2; ++k)
          acc[j][2 + n] = MFMA16(afA[j][k], bfB[n][k], acc[j][2 + n]);
    __builtin_amdgcn_s_setprio(0);

    // ---- phase 3: MFMA q10 ----
    stage_step();
    __builtin_amdgcn_s_setprio(1);
#pragma unroll
    for (int j = 0; j < 4; ++j)
#pragma unroll
      for (int n = 0; n < 2; ++n)
#pragma unroll
        for (int k = 0; k < 2; ++k)
          acc[4 + j][n] = MFMA16(afB[j][k], bfA[n][k], acc[4 + j][n]);
    __builtin_amdgcn_s_setprio(0);

    sA += 4; if (sA >= 10) sA -= 10;
    sB += 4; if (sB >= 10) sB -= 10;
  }
  // final q11 (last tile)
  __builtin_amdgcn_s_setprio(1);
#pragma unroll
  for (int j = 0; j < 4; ++j)
#pragma unroll
    for (int n = 0; n < 2; ++n)
#pragma unroll
      for (int k = 0; k < 2; ++k)
        acc[4 + j][2 + n] = MFMA16(afB[j][k], bfB[n][k], acc[4 + j][2 + n]);
  __builtin_amdgcn_s_setprio(0);

  // epilogue: C/D layout col=lane&15, row=(lane>>4)*4+reg
  const int rbase = bm + wr * 128 + ((lane >> 4) << 2);
  const int cbase = bn + wc * 64 + (lane & 15);
  float wv[8][4];
  if (EPI != 0) {
    const int ei = (EPI == 3) ? z : eidx;
#pragma unroll
    for (int mf = 0; mf < 8; ++mf)
#pragma unroll
      for (int r = 0; r < 4; ++r)
        wv[mf][r] = wgt[(size_t)(rbase + mf * 16 + r) * 8 + ei];
  }
#pragma unroll
  for (int mf = 0; mf < 8; ++mf) {
#pragma unroll
    for (int nf = 0; nf < 4; ++nf) {
      const int col = cbase + nf * 16;
      const float bv = bias[z * biasZ + col];
#pragma unroll
      for (int r = 0; r < 4; ++r) {
        const int row = rbase + mf * 16 + r;
        const float v = acc[mf][nf][r] + bv;
        if (EPI == 0) {
          Cb[z * cZ + (size_t)row * N + col] = f2bf(fast_gelu(v));
        } else if (EPI == 1) {
          Cf[(size_t)row * N + col] = wv[mf][r] * v;
        } else if (EPI == 2) {
          Cf[(size_t)row * N + col] += wv[mf][r] * v;
        } else {
          Cf[z * cZ + (size_t)row * N + col] = wv[mf][r] * v;
        }
      }
    }
  }
}

// ---------- gate logits (E=8) + softmax, 1 block/token ----------
__global__ void gate_softmax(const unsigned short* __restrict__ g2,
                             const unsigned short* __restrict__ W3,
                             const float* __restrict__ b3,
                             float* __restrict__ wout, int H) {
  const int m = blockIdx.x;
  const int lane = threadIdx.x & 63;
  const int wid  = threadIdx.x >> 6;
  float acc[8] = {0.f, 0.f, 0.f, 0.f, 0.f, 0.f, 0.f, 0.f};
  const unsigned short* grow = g2 + (size_t)m * H;
  for (int k = threadIdx.x * 8; k < H; k += 256 * 8) {
    short8 gv = *(const short8*)(grow + k);
    float gf[8];
#pragma unroll
    for (int j = 0; j < 8; ++j) gf[j] = bf2f((unsigned short)gv[j]);
#pragma unroll
    for (int e = 0; e < 8; ++e) {
      short8 wvv = *(const short8*)(W3 + (size_t)e * H + k);
#pragma unroll
      for (int j = 0; j < 8; ++j) acc[e] += gf[j] * bf2f((unsigned short)wvv[j]);
    }
  }
#pragma unroll
  for (int e = 0; e < 8; ++e)
#pragma unroll
    for (int off = 32; off > 0; off >>= 1) acc[e] += __shfl_down(acc[e], off);
  __shared__ float red[4][8];
  if (lane == 0) {
#pragma unroll
    for (int e = 0; e < 8; ++e) red[wid][e] = acc[e];
  }
  __syncthreads();
  if (threadIdx.x == 0) {
    float l[8], mx = -1e30f, s = 0.f;
#pragma unroll
    for (int e = 0; e < 8; ++e) {
      l[e] = red[0][e] + red[1][e] + red[2][e] + red[3][e] + b3[e];
      mx = fmaxf(mx, l[e]);
    }
#pragma unroll
    for (int e = 0; e < 8; ++e) { l[e] = expf(l[e] - mx); s += l[e]; }
    const float inv = 1.f / s;
#pragma unroll
    for (int e = 0; e < 8; ++e) wout[(size_t)m * 8 + e] = l[e] * inv;
  }
}

// ---------- sum of 8 expert partials ----------
__global__ void reduce8(const float4* __restrict__ in, float4* __restrict__ out,
                        int n4) {
  int i = blockIdx.x * 256 + threadIdx.x;
  const int stride = gridDim.x * 256;
  for (; i < n4; i += stride) {
    float4 s = in[i];
#pragma unroll
    for (int zz = 1; zz < 8; ++zz) {
      float4 v = in[(size_t)zz * n4 + i];
      s.x += v.x; s.y += v.y; s.z += v.z; s.w += v.w;
    }
    out[i] = s;
  }
}

extern "C" void kernel_launch(void* const* d_in, const int* in_sizes, int n_in,
                              void* d_out, int out_size, void* d_ws, size_t ws_size,
                              hipStream_t stream) {
  const float* x   = (const float*)d_in[0];
  const float* gW1 = (const float*)d_in[1];
  const float* gb1 = (const float*)d_in[2];
  const float* gW2 = (const float*)d_in[3];
  const float* gb2 = (const float*)d_in[4];
  const float* gW3 = (const float*)d_in[5];
  const float* gb3 = (const float*)d_in[6];
  const float* eW1 = (const float*)d_in[7];
  const float* eb1 = (const float*)d_in[8];
  const float* eW2 = (const float*)d_in[9];
  const float* eb2 = (const float*)d_in[10];

  const int M = 4096, D = 1024, H = 4096, E = 8;
  const int NCAT = (1 + E) * H;   // 36864: [gate1 | expert1 x8] fused columns

  float* outP = (float*)d_out;              // [M, D]
  float* wP   = outP + (size_t)M * D;       // [M, E]

  char* ws = (char*)d_ws;
  size_t off = 0;
  auto alloc = [&](size_t bytes) -> void* {
    void* p = ws + off;
    off += (bytes + 255) & ~(size_t)255;
    return p;
  };
  unsigned short* xb    = (unsigned short*)alloc((size_t)M * D * 2);
  unsigned short* w1cat = (unsigned short*)alloc((size_t)NCAT * D * 2);
  unsigned short* gW2b  = (unsigned short*)alloc((size_t)H * H * 2);
  unsigned short* gW3b  = (unsigned short*)alloc((size_t)E * H * 2);
  unsigned short* eW2b  = (unsigned short*)alloc((size_t)E * D * H * 2);
  unsigned short* g2b   = (unsigned short*)alloc((size_t)M * H * 2);
  float*          b1cat = (float*)alloc((size_t)NCAT * 4);
  unsigned short* h_cat = (unsigned short*)alloc((size_t)M * NCAT * 2);
  const size_t base_off = off;
  const size_t eo_b = (size_t)E * M * D * 4;   // 128 MB
  const int tier1 = (ws_size >= base_off + eo_b) ? 1 : 0;

  auto cvt = [&](const float* src, unsigned short* dst, size_t n) {
    size_t n4 = n >> 2;
    size_t b = (n4 + 255) >> 8;
    if (b > 2048) b = 2048;
    cvt_f32_bf16<<<dim3((unsigned)b), dim3(256), 0, stream>>>(
        (const float4*)src, (ushort4v*)dst, n4);
  };
  cvt(x,   xb,    (size_t)M * D);
  cvt(gW1, w1cat, (size_t)H * D);
  cvt(eW1, w1cat + (size_t)H * D, (size_t)E * H * D);
  cvt(gW2, gW2b,  (size_t)H * H);
  cvt(gW3, gW3b,  (size_t)E * H);
  cvt(eW2, eW2b,  (size_t)E * D * H);
  hipMemcpyAsync(b1cat, gb1, (size_t)H * 4, hipMemcpyDeviceToDevice, stream);
  hipMemcpyAsync(b1cat + H, eb1, (size_t)E * H * 4, hipMemcpyDeviceToDevice, stream);

  // fused layer-1: h_cat = gelu(x @ [gW1;eW1]^T + b1cat)   [M, 36864], K=D
  gemm256<0><<<dim3(NCAT / 256, M / 256, 1), dim3(512), 0, stream>>>(
      xb, 0, D, w1cat, 0, b1cat, 0, h_cat, nullptr, 0, nullptr, 0, M, NCAT, D);
  // gate2: g2 = gelu(g1 @ gW2^T + gb2)  [M,H], K=H  (A = h_cat cols [0,H))
  gemm256<0><<<dim3(H / 256, M / 256, 1), dim3(512), 0, stream>>>(
      h_cat, 0, NCAT, gW2b, 0, gb2, 0, g2b, nullptr, 0, nullptr, 0, M, H, H);
  // softmax weights
  gate_softmax<<<dim3(M), dim3(256), 0, stream>>>(g2b, gW3b, gb3, wP, H);

  if (tier1) {
    float* eo_all = (float*)alloc(eo_b);
    // expert layer 2 grouped -> weighted partials (A = h_cat cols [H+z*H, ...))
    gemm256<3><<<dim3(D / 256, M / 256, E), dim3(512), 0, stream>>>(
        h_cat + H, (size_t)H, NCAT, eW2b, (size_t)D * H, eb2, D,
        nullptr, eo_all, (size_t)M * D, wP, 0, M, D, H);
    reduce8<<<dim3(2048), dim3(256), 0, stream>>>(
        (const float4*)eo_all, (float4*)outP, (int)((size_t)M * D / 4));
  } else {
    for (int e = 0; e < E; ++e) {
      if (e == 0)
        gemm256<1><<<dim3(D / 256, M / 256, 1), dim3(512), 0, stream>>>(
            h_cat + (size_t)(1 + e) * H, 0, NCAT, eW2b + (size_t)e * D * H, 0,
            eb2 + (size_t)e * D, 0, nullptr, outP, 0, wP, e, M, D, H);
      else
        gemm256<2><<<dim3(D / 256, M / 256, 1), dim3(512), 0, stream>>>(
            h_cat + (size_t)(1 + e) * H, 0, NCAT, eW2b + (size_t)e * D * H, 0,
            eb2 + (size_t)e * D, 0, nullptr, outP, 0, wP, e, M, D, H);
    }
  }
}